// Round 2
// 917.436 us; speedup vs baseline: 1.1306x; 1.1306x over previous
//
#include <hip/hip_runtime.h>
#include <math.h>

typedef __attribute__((ext_vector_type(8))) short bf16x8;
typedef __attribute__((ext_vector_type(4))) float f32x4;

__device__ __forceinline__ float wsum64(float v) {
#pragma unroll
  for (int d = 32; d > 0; d >>= 1) v += __shfl_xor(v, d, 64);
  return v;
}

__device__ __forceinline__ unsigned short f2bf(float f) {
  unsigned u = __float_as_uint(f);
  u = (u + 0x7FFFu + ((u >> 16) & 1u)) >> 16;
  return (unsigned short)u;
}

// ---------------- K0: init (chadj extract + zero mean-sums) ----------------
__global__ void k_init(const float* __restrict__ smask, float* __restrict__ chadj,
                       double* __restrict__ sums) {
  int t = threadIdx.x;
  if (t < 4) sums[t] = 0.0;
  if (t < 484) {
    int c1 = t / 22, c2 = t % 22;
    chadj[t] = smask[(size_t)(c1 * 64) * 1408 + (size_t)c2 * 64];
  }
}

// ---------------- A: input GEMM: z (fp32 + bf16 + transposed) and h1-pre ----
__global__ __launch_bounds__(256) void k_gemm_in(
    const float* __restrict__ x, const float* __restrict__ projw,
    const float* __restrict__ w1, float* __restrict__ z, float* __restrict__ zT,
    unsigned short* __restrict__ zb, float* __restrict__ h1) {
  __shared__ float xs[16][68];
  __shared__ float wsT[16][68];
  __shared__ float ldsT[64][65];
  int n0 = blockIdx.x * 64;
  int o0 = blockIdx.y * 64;
  int tid = threadIdx.x;
  int tx = tid & 15, ty = tid >> 4;
  float acc[4][4];
#pragma unroll
  for (int i = 0; i < 4; i++)
#pragma unroll
    for (int j = 0; j < 4; j++) acc[i][j] = 0.f;
  for (int kc = 0; kc < 16; kc++) {
#pragma unroll
    for (int rep = 0; rep < 4; rep++) {
      int e = tid + rep * 256;
      int n = e >> 4, k = e & 15;
      xs[k][n] = x[(size_t)(n0 + n) * 256 + kc * 16 + k];
      int row = o0 + n;
      wsT[k][n] = (row < 256) ? projw[(size_t)row * 256 + kc * 16 + k]
                              : w1[(size_t)(row - 256) * 256 + kc * 16 + k];
    }
    __syncthreads();
#pragma unroll
    for (int k = 0; k < 16; k++) {
      float4 a4 = *(const float4*)&xs[k][4 * ty];
      float4 w4 = *(const float4*)&wsT[k][4 * tx];
      float ar[4] = {a4.x, a4.y, a4.z, a4.w};
      float wr[4] = {w4.x, w4.y, w4.z, w4.w};
#pragma unroll
      for (int i = 0; i < 4; i++)
#pragma unroll
        for (int j = 0; j < 4; j++) acc[i][j] = fmaf(ar[i], wr[j], acc[i][j]);
    }
    __syncthreads();
  }
  if (blockIdx.y >= 4) {
#pragma unroll
    for (int i = 0; i < 4; i++) {
      size_t base = (size_t)(n0 + 4 * ty + i) * 128 + (o0 - 256) + 4 * tx;
      float4 t;
      t.x = acc[i][0]; t.y = acc[i][1]; t.z = acc[i][2]; t.w = acc[i][3];
      *(float4*)&h1[base] = t;
    }
  } else {
#pragma unroll
    for (int i = 0; i < 4; i++) {
      size_t base = (size_t)(n0 + 4 * ty + i) * 256 + o0 + 4 * tx;
      float4 t;
      t.x = acc[i][0]; t.y = acc[i][1]; t.z = acc[i][2]; t.w = acc[i][3];
      *(float4*)&z[base] = t;
      unsigned lo = (unsigned)f2bf(acc[i][0]) | ((unsigned)f2bf(acc[i][1]) << 16);
      unsigned hi = (unsigned)f2bf(acc[i][2]) | ((unsigned)f2bf(acc[i][3]) << 16);
      uint2 u2; u2.x = lo; u2.y = hi;
      *(uint2*)(zb + base) = u2;
    }
    __syncthreads();
#pragma unroll
    for (int i = 0; i < 4; i++)
#pragma unroll
      for (int j = 0; j < 4; j++) ldsT[4 * tx + j][4 * ty + i] = acc[i][j];
    __syncthreads();
    int bblk = blockIdx.x / 22;
    int nbase = (blockIdx.x % 22) * 64;
#pragma unroll
    for (int rep = 0; rep < 16; rep++) {
      int e = tid + rep * 256;
      int oo = e >> 6, nn = e & 63;
      zT[(size_t)((bblk * 4 + blockIdx.y) * 64 + oo) * 1408 + nbase + nn] = ldsT[oo][nn];
    }
  }
}

// ---------------- B: per-node: sq per head, score (exact gelu), top-p gate --
__global__ __launch_bounds__(256) void k_node(
    const float* __restrict__ x, const float* __restrict__ z,
    const float* __restrict__ h1, const float* __restrict__ gw,
    const float* __restrict__ gb, const float* __restrict__ b1,
    const float* __restrict__ w2, const float* __restrict__ b2v,
    float* __restrict__ sq, float4* __restrict__ wnode) {
  int tid = threadIdx.x;
  int w = tid >> 6, lane = tid & 63;
  int node = blockIdx.x * 4 + w;
  int b = node / 1408, n = node % 1408;
  const float* zr = z + (size_t)node * 256;
  const float* xr = x + (size_t)node * 256;
#pragma unroll
  for (int c = 0; c < 4; c++) {
    float val = zr[c * 64 + lane];
    float s = wsum64(val * val);
    if (lane == 0) sq[(size_t)(b * 4 + c) * 1408 + n] = s;
  }
  float gl[3];
#pragma unroll
  for (int f = 0; f < 3; f++) {
    float p = 0.f;
#pragma unroll
    for (int c = 0; c < 4; c++)
      p = fmaf(xr[c * 64 + lane], gw[f * 256 + c * 64 + lane], p);
    gl[f] = wsum64(p) + gb[f];
  }
  const float* hr = h1 + (size_t)node * 128;
  float ps = 0.f;
#pragma unroll
  for (int c = 0; c < 2; c++) {
    float t = hr[c * 64 + lane] + b1[c * 64 + lane];
    float g = 0.5f * t * (1.f + erff(t * 0.7071067811865475f));
    ps = fmaf(g, w2[c * 64 + lane], ps);
  }
  float sc = wsum64(ps) + b2v[0];
  sc = 1.f / (1.f + expf(-sc));
  float mx = fmaxf(gl[0], fmaxf(gl[1], gl[2]));
  float ex[3];
  float esum = 0.f;
#pragma unroll
  for (int f = 0; f < 3; f++) { ex[f] = expf(gl[f] - mx); esum += ex[f]; }
  float p3[3];
#pragma unroll
  for (int f = 0; f < 3; f++) p3[f] = ex[f] / esum;
  int rk[3];
#pragma unroll
  for (int f = 0; f < 3; f++) {
    int r = 0;
#pragma unroll
    for (int g = 0; g < 3; g++)
      r += ((p3[g] > p3[f]) || (p3[g] == p3[f] && g < f)) ? 1 : 0;
    rk[f] = r;
  }
  float sp[3]; int oi[3];
#pragma unroll
  for (int f = 0; f < 3; f++) { sp[rk[f]] = p3[f]; oi[rk[f]] = f; }
  bool k1 = sp[0] < 0.85f;
  bool k2 = (sp[0] + sp[1]) < 0.85f;
  float wv[3];
  wv[oi[0]] = sp[0];
  wv[oi[1]] = k1 ? sp[1] : 0.f;
  wv[oi[2]] = k2 ? sp[2] : 0.f;
  float inv = 1.f / (wv[0] + wv[1] + wv[2] + 1e-8f);
  if (lane == 0) wnode[node] = make_float4(wv[0] * inv, wv[1] * inv, wv[2] * inv, sc);
}

// ---------------- P1: fp32 distances + exact top-k(211) select -> bitmap ----
// grid (88,16,4); block 256 = 4 waves. Wave w owns a CONTIGUOUS range of
// j-tiles (w0:0-5, w1:6-11, w2:12-16, w3:17-21) so the 5-6 B loads per k
// share one pointer + 256B immediate offsets, and no dummy tiles are
// computed. Selection is ONE-SHOT for all 16 rows: 512-bin histogram with
// two rows packed per u32 (u16 halves), 5 barriers total. d^2 values are
// bit-identical to the previous version (same fmaf order), so the selected
// bitmap is unchanged.
template <int TC>
__device__ __forceinline__ void dotstrip16(float (&v)[16][6],
                                           const float* __restrict__ zTh,
                                           const float (&As)[64][16], int jb) {
#pragma unroll
  for (int r = 0; r < 16; r++)
#pragma unroll
    for (int t = 0; t < TC; t++) v[r][t] = 0.f;
  const float* bp = zTh + jb;
  float bc[TC];
#pragma unroll
  for (int t = 0; t < TC; t++) bc[t] = bp[t * 64];
  const float* pn = bp + 1408;
#pragma unroll 1
  for (int k = 0; k < 63; k++) {
    float bn[TC];
#pragma unroll
    for (int t = 0; t < TC; t++) bn[t] = pn[t * 64];
    pn += 1408;
    float4 a0 = *(const float4*)&As[k][0];
    float4 a1 = *(const float4*)&As[k][4];
    float4 a2 = *(const float4*)&As[k][8];
    float4 a3 = *(const float4*)&As[k][12];
    float ar[16] = {a0.x, a0.y, a0.z, a0.w, a1.x, a1.y, a1.z, a1.w,
                    a2.x, a2.y, a2.z, a2.w, a3.x, a3.y, a3.z, a3.w};
#pragma unroll
    for (int r = 0; r < 16; r++)
#pragma unroll
      for (int t = 0; t < TC; t++) v[r][t] = fmaf(ar[r], bc[t], v[r][t]);
#pragma unroll
    for (int t = 0; t < TC; t++) bc[t] = bn[t];
  }
  {
    float4 a0 = *(const float4*)&As[63][0];
    float4 a1 = *(const float4*)&As[63][4];
    float4 a2 = *(const float4*)&As[63][8];
    float4 a3 = *(const float4*)&As[63][12];
    float ar[16] = {a0.x, a0.y, a0.z, a0.w, a1.x, a1.y, a1.z, a1.w,
                    a2.x, a2.y, a2.z, a2.w, a3.x, a3.y, a3.z, a3.w};
#pragma unroll
    for (int r = 0; r < 16; r++)
#pragma unroll
      for (int t = 0; t < TC; t++) v[r][t] = fmaf(ar[r], bc[t], v[r][t]);
  }
}

__global__ __launch_bounds__(256, 3) void k_pass1(
    const float* __restrict__ zT, const float* __restrict__ sq,
    unsigned* __restrict__ bm, double* __restrict__ sums) {
  __shared__ float As[64][16];
  __shared__ float srowL[16];
  __shared__ unsigned hist[8][528];   // rows 2r,2r+1 packed u16; idx = key + (key>>6)
  __shared__ float cand[16][128];
  __shared__ unsigned candCnt[16];
  __shared__ int tbinS[16], rstarS[16];
  __shared__ float TS[16];
  int b = blockIdx.y, h = blockIdx.z;
  int i0 = blockIdx.x * 16;
  int tid = threadIdx.x;
  int w = tid >> 6, lane = tid & 63;
  const float* zTh = zT + (size_t)((b * 4 + h) * 64) * 1408;
  const float* sqh = sq + (size_t)(b * 4 + h) * 1408;
#pragma unroll
  for (int rep = 0; rep < 4; rep++) {
    int e = tid + rep * 256;
    int k = e >> 4, r = e & 15;
    As[k][r] = zTh[(size_t)k * 1408 + i0 + r];
  }
  if (tid < 16) srowL[tid] = sqh[i0 + tid];
  {
    unsigned* histF = &hist[0][0];
    for (int u = tid; u < 8 * 528; u += 256) histF[u] = 0u;
  }
  if (tid < 16) candCnt[tid] = 0u;
  __syncthreads();

  const int TC = (w < 2) ? 6 : 5;            // tiles per wave (22 = 6+6+5+5)
  const int tbase = (w < 2) ? 6 * w : 5 * w + 2;
  int jb = tbase * 64 + lane;
  float sqj[6];
#pragma unroll
  for (int t = 0; t < 6; t++)
    sqj[t] = (t < 5 || TC == 6) ? sqh[jb + t * 64] : 0.f;

  float v[16][6];
  if (w < 2) dotstrip16<6>(v, zTh, As, jb);
  else       dotstrip16<5>(v, zTh, As, jb);

  // finalize: dot -> clamped d^2, accumulate sqrt-sum, fill histogram
  float ssum = 0.f;
#pragma unroll
  for (int r = 0; r < 16; r++) {
    float sr = srowL[r];
#pragma unroll
    for (int t = 0; t < 6; t++) {
      if (t < 5 || TC == 6) {
        float d = sr + sqj[t] - 2.f * v[r][t];
        d = fmaxf(d, 0.f);
        ssum += sqrtf(d);
        v[r][t] = d;
        unsigned key = (unsigned)fminf(d * 4.0f, 511.0f);
        atomicAdd(&hist[r >> 1][key + (key >> 6)], 1u << ((r & 1) * 16));
      }
    }
  }
  __syncthreads();

  // scan: wave w handles rows 4w..4w+3; find threshold bin + in-bin rank
#pragma unroll 1
  for (int q = 0; q < 4; q++) {
    int r = 4 * w + q;
    int sh = (r & 1) * 16;
    const unsigned* hrow = hist[r >> 1];
    unsigned partial = 0;
#pragma unroll
    for (int u = 0; u < 8; u++) {
      int bin = 8 * lane + u;
      partial += (hrow[bin + (bin >> 6)] >> sh) & 0xffffu;
    }
    unsigned inc = partial;
#pragma unroll
    for (int d = 1; d < 64; d <<= 1) {
      unsigned u2 = __shfl_up(inc, d, 64);
      if (lane >= d) inc += u2;
    }
    unsigned long long mk = __ballot(inc >= 211u);
    int Ls = __ffsll(mk) - 1;
    unsigned cbefore = (Ls > 0) ? (unsigned)__shfl((int)inc, Ls - 1, 64) : 0u;
    int tb = -1;
    unsigned run = cbefore, cbelow = cbefore;
#pragma unroll
    for (int u = 0; u < 8; u++) {
      int bin = 8 * Ls + u;
      unsigned c = (hrow[bin + (bin >> 6)] >> sh) & 0xffffu;
      if (tb < 0) {
        if (run + c >= 211u) { tb = bin; cbelow = run; }
        run += c;
      }
    }
    if (lane == 0) { tbinS[r] = tb; rstarS[r] = 211 - (int)cbelow; }
  }
  __syncthreads();

  // candidate collect (all threads, all 16 rows)
#pragma unroll
  for (int r = 0; r < 16; r++) {
    int tb = tbinS[r];
#pragma unroll
    for (int t = 0; t < 6; t++) {
      if (t < 5 || TC == 6) {
        float d = v[r][t];
        unsigned key = (unsigned)fminf(d * 4.0f, 511.0f);
        if ((int)key == tb) {
          unsigned id = atomicAdd(&candCnt[r], 1u);
          if (id < 128u) cand[r][id] = d;
        }
      }
    }
  }
  __syncthreads();

  // rank within threshold bin: wave w ranks rows 4w..4w+3
#pragma unroll 1
  for (int q = 0; q < 4; q++) {
    int r = 4 * w + q;
    int rstar = rstarS[r];
    unsigned craw = candCnt[r];
    int cnt = (craw > 128u) ? 128 : (int)craw;
    float t2l = INFINITY;
    for (int base = 0; base < cnt; base += 64) {
      int ci = base + lane;
      if (ci < cnt) {
        float xm = cand[r][ci];
        int below = 0, eq = 0;
        for (int m = 0; m < cnt; m++) {
          float y = cand[r][m];
          below += (y < xm) ? 1 : 0;
          eq += (y == xm) ? 1 : 0;
        }
        if (below < rstar && rstar <= below + eq) t2l = fminf(t2l, xm);
      }
    }
#pragma unroll
    for (int dd = 32; dd > 0; dd >>= 1) t2l = fminf(t2l, __shfl_xor(t2l, dd, 64));
    if (lane == 0) TS[r] = t2l;
  }
  __syncthreads();

  // bitmap: 1 ballot = 1 tile of 64 j; wave w writes its own tiles
#pragma unroll
  for (int r = 0; r < 16; r++) {
    float T = TS[r];
    unsigned* bmrow = bm + (size_t)((h * 16 + b) * 1408 + i0 + r) * 44;
#pragma unroll
    for (int t = 0; t < 6; t++) {
      if (t < 5 || TC == 6) {
        unsigned long long bl = __ballot(v[r][t] <= T);
        int tile = tbase + t;
        if (lane == 0) bmrow[tile * 2] = (unsigned)bl;
        if (lane == 32) bmrow[tile * 2 + 1] = (unsigned)(bl >> 32);
      }
    }
  }
  ssum = wsum64(ssum);
  if (lane == 0) atomicAdd(&sums[h], (double)ssum);
}

// ---------------- E: bf16-MFMA recompute + fused epilogue -> out ------------
__global__ __launch_bounds__(256) void k_final(
    const unsigned short* __restrict__ zb, const float* __restrict__ sq,
    const float4* __restrict__ wnode, const unsigned* __restrict__ bm,
    const double* __restrict__ sums, const float* __restrict__ chadj,
    const float* __restrict__ thrp, float* __restrict__ out) {
  int it = blockIdx.x, jt = blockIdx.y, b = blockIdx.z;
  int tid = threadIdx.x, wv = tid >> 6, lane = tid & 63;
  int quad = lane >> 4, l15 = lane & 15;
  float c2h[4];
#pragma unroll
  for (int h = 0; h < 4; h++) {
    double mu = sums[h] * (1.0 / (16.0 * 1408.0 * 1408.0));
    c2h[h] = (float)(1.0 / (2.0 * mu * mu + 1e-8)) * 1.44269504088896f;
  }
  float thr = thrp[0];
  int ib = it * 64 + wv * 16;
  const unsigned short* za = zb + (size_t)(b * 1408 + ib + l15) * 256;
  bf16x8 af[4][2];
#pragma unroll
  for (int h = 0; h < 4; h++)
#pragma unroll
    for (int k0 = 0; k0 < 2; k0++)
      af[h][k0] = *(const bf16x8*)(za + h * 64 + k0 * 32 + quad * 8);
  int ibq = ib + quad * 4;
  float4 wi[4];
  float sqi[4][4];
#pragma unroll
  for (int reg = 0; reg < 4; reg++) {
    int i = ibq + reg;
    wi[reg] = wnode[b * 1408 + i];
#pragma unroll
    for (int h = 0; h < 4; h++) sqi[reg][h] = sq[(size_t)(b * 4 + h) * 1408 + i];
  }
#pragma unroll
  for (int js = 0; js < 4; js++) {
    int j = jt * 64 + js * 16 + l15;
    const unsigned short* zj = zb + (size_t)(b * 1408 + j) * 256;
    f32x4 acc[4];
#pragma unroll
    for (int h = 0; h < 4; h++) {
      bf16x8 b0 = *(const bf16x8*)(zj + h * 64 + quad * 8);
      bf16x8 b1f = *(const bf16x8*)(zj + h * 64 + 32 + quad * 8);
      f32x4 a = {0.f, 0.f, 0.f, 0.f};
      a = __builtin_amdgcn_mfma_f32_16x16x32_bf16(af[h][0], b0, a, 0, 0, 0);
      a = __builtin_amdgcn_mfma_f32_16x16x32_bf16(af[h][1], b1f, a, 0, 0, 0);
      acc[h] = a;
    }
    float sqj[4];
#pragma unroll
    for (int h = 0; h < 4; h++) sqj[h] = sq[(size_t)(b * 4 + h) * 1408 + j];
    float4 wj = wnode[b * 1408 + j];
    float adjv[4] = {0.f, 0.f, 0.f, 0.f};
#pragma unroll
    for (int h = 0; h < 4; h++) {
      const unsigned* bmh = bm + (size_t)(h * 16 + b) * 1408 * 44;
      unsigned wJ = bmh[(size_t)j * 44 + (ibq >> 5)];
#pragma unroll
      for (int reg = 0; reg < 4; reg++) {
        int i = ibq + reg;
        float d2 = sqi[reg][h] + sqj[h] - 2.f * acc[h][reg];
        d2 = fmaxf(d2, 0.f);
        float sim = exp2f(-d2 * c2h[h]);
        unsigned bi = bmh[(size_t)i * 44 + (j >> 5)] >> (j & 31);
        unsigned bj = wJ >> (i & 31);
        adjv[reg] += (((bi | bj) & 1u) != 0u) ? sim : 0.f;
      }
    }
#pragma unroll
    for (int reg = 0; reg < 4; reg++) {
      int i = ibq + reg;
      int chi = i >> 6, pi = i & 63, chj = j >> 6, pj = j & 63;
      float e0 = 0.5f * (wi[reg].x + wj.x);
      float e1 = 0.5f * (wi[reg].y + wj.y);
      float e2 = 0.5f * (wi[reg].z + wj.z);
      float a2 = 0.f;
      if (chi == chj) {
        int dp = pi - pj;
        if (dp == 1 || dp == -1) a2 += e0;
      }
      if (pi == pj && chadj[chi * 22 + chj] != 0.f) a2 += e1;
      float xw = (wi[reg].w * wj.w - thr) * 10.f;
      float pt = 1.f / (1.f + exp2f(-xw * 1.44269504088896f));
      a2 += pt * e2;
      out[(size_t)(b * 1408 + i) * 1408 + j] = 0.25f * adjv[reg] * a2;
    }
  }
}

// ---------------------------------------------------------------------------
extern "C" void kernel_launch(void* const* d_in, const int* in_sizes, int n_in,
                              void* d_out, int out_size, void* d_ws, size_t ws_size,
                              hipStream_t stream) {
  (void)in_sizes; (void)n_in; (void)out_size; (void)ws_size;
  const float* x = (const float*)d_in[0];
  const float* projw = (const float*)d_in[1];
  const float* gw = (const float*)d_in[2];
  const float* gb = (const float*)d_in[3];
  const float* w1 = (const float*)d_in[4];
  const float* b1 = (const float*)d_in[5];
  const float* w2 = (const float*)d_in[6];
  const float* b2 = (const float*)d_in[7];
  const float* thr = (const float*)d_in[8];
  const float* smask = (const float*)d_in[10];
  float* out = (float*)d_out;
  char* ws = (char*)d_ws;
  size_t off = 0;
  auto take = [&](size_t bytes) {
    char* p = ws + off;
    off += (bytes + 255) & ~(size_t)255;
    return p;
  };
  float* z = (float*)take((size_t)22528 * 256 * 4);
  float* zT = (float*)take((size_t)22528 * 256 * 4);
  unsigned short* zb = (unsigned short*)take((size_t)22528 * 256 * 2);
  float* h1 = (float*)take((size_t)22528 * 128 * 4);
  float* sq = (float*)take((size_t)16 * 4 * 1408 * 4);
  float4* wnode = (float4*)take((size_t)22528 * 16);
  unsigned* bm = (unsigned*)take((size_t)4 * 16 * 1408 * 44 * 4);
  float* chadj = (float*)take(484 * 4);
  double* sums = (double*)take(4 * 8);

  hipLaunchKernelGGL(k_init, dim3(1), dim3(512), 0, stream, smask, chadj, sums);
  hipLaunchKernelGGL(k_gemm_in, dim3(352, 6), dim3(256), 0, stream, x, projw, w1,
                     z, zT, zb, h1);
  hipLaunchKernelGGL(k_node, dim3(5632), dim3(256), 0, stream, x, z, h1, gw, gb,
                     b1, w2, b2, sq, wnode);
  hipLaunchKernelGGL(k_pass1, dim3(88, 16, 4), dim3(256), 0, stream, zT, sq, bm,
                     sums);
  hipLaunchKernelGGL(k_final, dim3(22, 22, 16), dim3(256), 0, stream, zb, sq,
                     wnode, bm, sums, chadj, thr, out);
}